// Round 8
// baseline (111.355 us; speedup 1.0000x reference)
//
#include <hip/hip_runtime.h>
#include <cstdint>
#include <cstddef>

typedef __attribute__((ext_vector_type(4))) float f32x4;
typedef __attribute__((ext_vector_type(2))) float f32x2;
typedef __bf16 bf16x8 __attribute__((ext_vector_type(8)));
typedef __attribute__((ext_vector_type(4))) unsigned int u32x4;
typedef __attribute__((ext_vector_type(2))) unsigned int u32x2;

#define DEVI __device__ __forceinline__

static constexpr int NB = 4;      // batches
static constexpr int NPTS = 8192; // N query points
static constexpr int SPTS = 2048; // S source points
static constexpr int DF = 256;    // feature dim of points1/points2
static constexpr int CIN = 512;   // concat width = 2*DF = K of GEMM1
static constexpr int MTOT = NB * NPTS; // 32768 rows

DEVI unsigned short f2b(float f) {
  union { float f; unsigned u; } v; v.f = f;
  unsigned r = v.u + 0x7FFFu + ((v.u >> 16) & 1u);
  return (unsigned short)(r >> 16);
}
DEVI float b2f(unsigned short h) {
  union { unsigned u; float f; } v; v.u = ((unsigned)h) << 16;
  return v.f;
}

typedef const __attribute__((address_space(1))) unsigned int* gas_t;
typedef __attribute__((address_space(3))) unsigned int* las_t;
DEVI void gload16(const void* g, void* l) {
  // async global->LDS, 16B per lane; LDS dest = uniform base + lane*16
  __builtin_amdgcn_global_load_lds((gas_t)g, (las_t)l, 16, 0, 0);
}

// ---------------- fused pre + knn: ONE dispatch, independent block roles.
// blocks [0,2048): points1 -> Abuf[:,0:256] ; [2048,2560): points2 -> P2T
// [2560,2624): w0 -> W0T ; [2624,2656): w1 -> W1T ; 2656: BN fold
// blocks [2657,3169): 3-NN — LAST so they land spread across all 256 CUs
// as the short BW-bound transpose blocks drain (knn-first crammed them onto
// ~170 CUs; R7 profile: 45µs @ 48% occupancy).
// LDS: 43.5KB union -> 3 blocks/CU.
__global__ __launch_bounds__(512) void preknn_kernel(
    const float* __restrict__ xyz1, const float* __restrict__ xyz2,
    const float* __restrict__ points1, const float* __restrict__ points2,
    const float* __restrict__ w0, const float* __restrict__ w1,
    unsigned short* __restrict__ Abuf, unsigned short* __restrict__ P2T,
    unsigned short* __restrict__ W0T, unsigned short* __restrict__ W1T,
    int* __restrict__ oidx, float* __restrict__ ow,
    const float* __restrict__ b0, const float* __restrict__ g0, const float* __restrict__ be0,
    const float* __restrict__ m0, const float* __restrict__ v0,
    const float* __restrict__ b1, const float* __restrict__ g1, const float* __restrict__ be1,
    const float* __restrict__ m1, const float* __restrict__ v1,
    float* __restrict__ sc0, float* __restrict__ sh0,
    float* __restrict__ sc1, float* __restrict__ sh1) {
  __shared__ __align__(16) char ldsbuf[43520];
  const int bid = blockIdx.x;

  if (bid >= 2657) {
    // ---- 3-NN, wave-parallel over S, branchless top-3, packed-f32 pairs.
    // LDS layout: spA[j]={x(2j),x(2j+1),y(2j),y(2j+1)}, spB[j]={z.,z.,w.,w.}
    f32x4* spA = reinterpret_cast<f32x4*>(ldsbuf);                            // 16KB
    f32x4* spB = reinterpret_cast<f32x4*>(ldsbuf + 16384);                    // 16KB
    float (*md)[64][3] = reinterpret_cast<float(*)[64][3]>(ldsbuf + 32768);   // 5376B
    int   (*mi)[64][3] = reinterpret_cast<int(*)[64][3]>(ldsbuf + 38144);     // 5376B
    const int kidx = bid - 2657;
    const int batch = kidx >> 7;
    const int nbase = (kidx & 127) << 6;
    const float* xb = xyz2 + (size_t)batch * 3 * SPTS;
    for (int i = threadIdx.x; i < SPTS; i += 512) {
      float a = xb[i], b = xb[SPTS + i], c = xb[2 * SPTS + i];
      float w = __fadd_rn(__fadd_rn(__fmul_rn(a, a), __fmul_rn(b, b)), __fmul_rn(c, c));
      const int j = i >> 1, h = i & 1;
      float* pA = reinterpret_cast<float*>(&spA[j]);
      float* pB = reinterpret_cast<float*>(&spB[j]);
      pA[h] = a; pA[2 + h] = b;
      pB[h] = c; pB[2 + h] = w;
    }
    __syncthreads();
    const int lane = threadIdx.x & 63, wave = threadIdx.x >> 6;
    const int n = nbase + lane;
    const float* q = xyz1 + (size_t)batch * 3 * NPTS;
    const float x = q[n], y = q[NPTS + n], z = q[2 * NPTS + n];
    const float qa = __fadd_rn(__fadd_rn(__fmul_rn(x, x), __fmul_rn(y, y)), __fmul_rn(z, z));
    // broadcast pairs for VOP3P (each half = same scalar)
    const f32x2 xq2 = {x, x}, yq2 = {y, y}, zq2 = {z, z};
    const f32x2 qa2 = {qa, qa}, n2 = {-2.0f, -2.0f};
    float d0 = 3.4e38f, d1 = 3.4e38f, d2 = 3.4e38f;
    int i0 = 0, i1 = 0, i2 = 0;
    const int j0 = wave << 7;   // 128 source-pairs per wave
#pragma unroll 4
    for (int j = j0; j < j0 + 128; ++j) {
      f32x4 a = spA[j];
      f32x4 b = spB[j];
      f32x2 xx = {a.x, a.y}, yy = {a.z, a.w};
      f32x2 zz = {b.x, b.y}, ww = {b.z, b.w};
      f32x2 dot, t, sqp;
      // per half: dot = fma(z,zq, fma(y,yq, mul(x,xq))); t = add(qa,w);
      // sq = fma(-2,dot,t) — byte-identical to the scalar reference chain.
      asm("v_pk_mul_f32 %0, %1, %2" : "=v"(dot) : "v"(xx), "v"(xq2));
      asm("v_pk_fma_f32 %0, %1, %2, %3" : "=v"(dot) : "v"(yy), "v"(yq2), "v"(dot));
      asm("v_pk_fma_f32 %0, %1, %2, %3" : "=v"(dot) : "v"(zz), "v"(zq2), "v"(dot));
      asm("v_pk_add_f32 %0, %1, %2" : "=v"(t) : "v"(qa2), "v"(ww));
      asm("v_pk_fma_f32 %0, %1, %2, %3" : "=v"(sqp) : "v"(n2), "v"(dot), "v"(t));
      {
        const float sq = sqp.x; const int s = 2 * j;
        const bool c0 = sq < d0, c1 = sq < d1, c2 = sq < d2;
        d2 = c1 ? d1 : (c2 ? sq : d2);
        i2 = c1 ? i1 : (c2 ? s : i2);
        d1 = c0 ? d0 : (c1 ? sq : d1);
        i1 = c0 ? i0 : (c1 ? s : i1);
        d0 = c0 ? sq : d0;
        i0 = c0 ? s : i0;
      }
      {
        const float sq = sqp.y; const int s = 2 * j + 1;
        const bool c0 = sq < d0, c1 = sq < d1, c2 = sq < d2;
        d2 = c1 ? d1 : (c2 ? sq : d2);
        i2 = c1 ? i1 : (c2 ? s : i2);
        d1 = c0 ? d0 : (c1 ? sq : d1);
        i1 = c0 ? i0 : (c1 ? s : i1);
        d0 = c0 ? sq : d0;
        i0 = c0 ? s : i0;
      }
    }
    if (wave != 0) {
      md[wave - 1][lane][0] = d0; mi[wave - 1][lane][0] = i0;
      md[wave - 1][lane][1] = d1; mi[wave - 1][lane][1] = i1;
      md[wave - 1][lane][2] = d2; mi[wave - 1][lane][2] = i2;
    }
    __syncthreads();
    if (wave != 0) return;
#pragma unroll
    for (int w = 0; w < 7; ++w) {
#pragma unroll
      for (int j = 0; j < 3; ++j) {
        float sq = md[w][lane][j];
        int si = mi[w][lane][j];
        const bool c0 = sq < d0, c1 = sq < d1, c2 = sq < d2;
        d2 = c1 ? d1 : (c2 ? sq : d2);
        i2 = c1 ? i1 : (c2 ? si : i2);
        d1 = c0 ? d0 : (c1 ? sq : d1);
        i1 = c0 ? i0 : (c1 ? si : i1);
        d0 = c0 ? sq : d0;
        i0 = c0 ? si : i0;
      }
    }
    float w0v = 1.0f / fmaxf(d0, 1e-10f);
    float w1v = 1.0f / fmaxf(d1, 1e-10f);
    float w2v = 1.0f / fmaxf(d2, 1e-10f);
    float sum = __fadd_rn(__fadd_rn(w0v, w1v), w2v);
    const int p = batch * NPTS + n;
    oidx[3 * p + 0] = i0; oidx[3 * p + 1] = i1; oidx[3 * p + 2] = i2;
    ow[3 * p + 0] = w0v / sum; ow[3 * p + 1] = w1v / sum; ow[3 * p + 2] = w2v / sum;
    return;
  }

  if (bid == 2656) {
    // ---- BN param folding
    const int t = threadIdx.x;
    if (t < 512) {
      float s = g0[t] / sqrtf(v0[t] + 1e-3f);
      sc0[t] = s;
      sh0[t] = (b0[t] - m0[t]) * s + be0[t];
    }
    if (t < 256) {
      float s = g1[t] / sqrtf(v1[t] + 1e-3f);
      sc1[t] = s;
      sh1[t] = (b1[t] - m1[t]) * s + be1[t];
    }
    return;
  }

  // ---- tiled transpose + f32->bf16 cast (512 threads: 8 rows/iter)
  float (*tile)[65] = reinterpret_cast<float(*)[65]>(ldsbuf);
  const float* in; unsigned short* out;
  int cols, tpr, ldo, tl;
  if (bid < 2048) {
    const int b = bid >> 9; tl = bid & 511;
    in = points1 + (size_t)b * DF * NPTS;
    out = Abuf + (size_t)b * NPTS * CIN;
    cols = NPTS; tpr = 128; ldo = CIN;
  } else if (bid < 2560) {
    const int i2b = bid - 2048; const int b = i2b >> 7; tl = i2b & 127;
    in = points2 + (size_t)b * DF * SPTS;
    out = P2T + (size_t)b * SPTS * DF;
    cols = SPTS; tpr = 32; ldo = DF;
  } else if (bid < 2624) {
    tl = bid - 2560; in = w0; out = W0T; cols = 512; tpr = 8; ldo = 512;
  } else {
    tl = bid - 2624; in = w1; out = W1T; cols = 256; tpr = 4; ldo = 512;
  }
  const int tr = (tl / tpr) * 64, tc = (tl % tpr) * 64;
  const int lx = threadIdx.x & 63, ly = threadIdx.x >> 6;
#pragma unroll
  for (int i = ly; i < 64; i += 8)
    tile[i][lx] = in[(size_t)(tr + i) * cols + tc + lx];
  __syncthreads();
#pragma unroll
  for (int i = ly; i < 64; i += 8)
    out[(size_t)(tc + i) * ldo + tr + lx] = f2b(tile[lx][i]);
}

// ---------------- interpolation: 2 points per wave (32 lanes x 16B per row).
__global__ __launch_bounds__(256) void interp_kernel(
    const unsigned short* __restrict__ p2t, const int* __restrict__ oidx,
    const float* __restrict__ ow, unsigned short* __restrict__ A) {
  const int l = threadIdx.x & 63;
  const int lo = l & 31;
  const int p = blockIdx.x * 8 + ((threadIdx.x >> 6) << 1) + (l >> 5);
  const int b = p >> 13;
  float a[8] = {};
#pragma unroll
  for (int k = 0; k < 3; ++k) {
    const int id = oidx[3 * p + k];
    const float w = ow[3 * p + k];
    const unsigned short* row = p2t + ((size_t)b * SPTS + id) * DF + lo * 8;
    u32x4 v = *reinterpret_cast<const u32x4*>(row);
#pragma unroll
    for (int j = 0; j < 4; ++j) {
      a[2 * j + 0] = __builtin_fmaf(w, b2f((unsigned short)(v[j] & 0xffff)), a[2 * j + 0]);
      a[2 * j + 1] = __builtin_fmaf(w, b2f((unsigned short)(v[j] >> 16)), a[2 * j + 1]);
    }
  }
  u32x4 o;
#pragma unroll
  for (int j = 0; j < 4; ++j)
    o[j] = (unsigned)f2b(a[2 * j + 0]) | ((unsigned)f2b(a[2 * j + 1]) << 16);
  *reinterpret_cast<u32x4*>(A + (size_t)p * CIN + DF + lo * 8) = o;
}

// ---------------- GEMM1: 256x256 tile, BK=64, 8 waves (2Mx4N), acc[8][4].
// H[M,512] = bf16(relu((A[M,512]*W0T^T)*scale+shift)). 2-phase dbuf,
// global_load_lds w16 pre-swizzled source, 128KB LDS.
__global__ __launch_bounds__(512, 2) void gemm1_kernel(
    const unsigned short* __restrict__ Abuf, const unsigned short* __restrict__ BT,
    const float* __restrict__ scale, const float* __restrict__ shift,
    unsigned short* __restrict__ H) {
  __shared__ u32x4 lsA[2][2048];  // 64KB
  __shared__ u32x4 lsB[2][2048];  // 64KB
  const int wg = (blockIdx.x & 7) * (gridDim.x >> 3) + (blockIdx.x >> 3);
  const int bn = wg & 1, bm = wg >> 1;
  const int t = threadIdx.x;
  const int lane = t & 63, wave = t >> 6;
  const int wm = wave >> 2, wn = wave & 3;  // 2 M-slabs(128) x 4 N-slabs(64)
  f32x4 acc[8][4] = {};
  const size_t arow0 = (size_t)bm * 256;
  const size_t brow0 = (size_t)bn * 256;

  auto stage = [&](int buf, int kb) {
    const int kbase = kb * 64;
#pragma unroll
    for (int i = 0; i < 4; ++i) {
      const int c = t + 512 * i;            // chunk 0..2047
      const int row = c >> 3;
      const int k16 = (c & 7) ^ (row & 7);  // inverse-swizzled source
      gload16(Abuf + (arow0 + row) * 512 + kbase + k16 * 8,
              &lsA[buf][512 * i + wave * 64]);
      gload16(BT + (brow0 + row) * 512 + kbase + k16 * 8,
              &lsB[buf][512 * i + wave * 64]);
    }
  };

  stage(0, 0);
  __syncthreads();
  int cur = 0;
  for (int kb = 0; kb < 8; ++kb) {
    if (kb < 7) stage(cur ^ 1, kb + 1);  // async prefetch overlaps compute
#pragma unroll
    for (int kk = 0; kk < 2; ++kk) {
      bf16x8 af[8], bfv[4];
      const int c16 = kk * 4 + (lane >> 4);
#pragma unroll
      for (int mi = 0; mi < 8; ++mi) {
        int row = wm * 128 + mi * 16 + (lane & 15);
        af[mi] = __builtin_bit_cast(bf16x8, lsA[cur][row * 8 + (c16 ^ (row & 7))]);
      }
#pragma unroll
      for (int ni = 0; ni < 4; ++ni) {
        int row = wn * 64 + ni * 16 + (lane & 15);
        bfv[ni] = __builtin_bit_cast(bf16x8, lsB[cur][row * 8 + (c16 ^ (row & 7))]);
      }
#pragma unroll
      for (int mi = 0; mi < 8; ++mi)
#pragma unroll
        for (int ni = 0; ni < 4; ++ni)
          acc[mi][ni] = __builtin_amdgcn_mfma_f32_16x16x32_bf16(af[mi], bfv[ni], acc[mi][ni], 0, 0, 0);
    }
    __syncthreads();
    cur ^= 1;
  }
  const int colb = bn * 256 + wn * 64;
  const int rowb = bm * 256 + wm * 128;
#pragma unroll
  for (int ni = 0; ni < 4; ++ni) {
    const int col = colb + ni * 16 + (lane & 15);
    const float sc = scale[col], shv = shift[col];
#pragma unroll
    for (int mi = 0; mi < 8; ++mi) {
      const int r0 = rowb + mi * 16 + ((lane >> 4) * 4);
#pragma unroll
      for (int j = 0; j < 4; ++j) {
        float v = fmaxf(__builtin_fmaf(acc[mi][ni][j], sc, shv), 0.0f);
        H[(size_t)(r0 + j) * 512 + col] = f2b(v);
      }
    }
  }
}

// ---------------- GEMM2 (128x128, 4 waves, 2-phase dbuf).
// out f32 [B][256][N]: C-tile routed through LDS then coalesced f32x4 stores.
__global__ __launch_bounds__(256) void gemm2_kernel(
    const unsigned short* __restrict__ Abuf, const unsigned short* __restrict__ BT,
    const float* __restrict__ scale, const float* __restrict__ shift,
    float* __restrict__ outp, int gridN) {
  __shared__ u32x4 sh[4096];  // 64KB: [0..2047]=A dbuf, [2048..4095]=B dbuf
  const int wg = (blockIdx.x & 7) * (gridDim.x >> 3) + (blockIdx.x >> 3);
  const int bn = wg % gridN, bm = wg / gridN;
  const int t = threadIdx.x;
  const int lane = t & 63, wave = t >> 6;
  const int wm = wave >> 1, wn = wave & 1;
  f32x4 acc[4][4] = {};
  const size_t arow0 = (size_t)bm * 128;
  const size_t brow0 = (size_t)bn * 128;

  auto stage = [&](int buf, int kb) {
    const int kbase = kb * 64;
#pragma unroll
    for (int i = 0; i < 4; ++i) {
      const int c = wave * 256 + i * 64 + lane;     // chunk index 0..1023
      const int row = c >> 3;
      const int k16 = (c & 7) ^ (row & 7);          // inverse-swizzled source
      gload16(Abuf + (arow0 + row) * 512 + kbase + k16 * 8,
              &sh[buf * 1024 + wave * 256 + i * 64]);
      gload16(BT + (brow0 + row) * 512 + kbase + k16 * 8,
              &sh[2048 + buf * 1024 + wave * 256 + i * 64]);
    }
  };

  stage(0, 0);
  __syncthreads();
  int cur = 0;
  for (int kb = 0; kb < 8; ++kb) {
    if (kb < 7) stage(cur ^ 1, kb + 1);
#pragma unroll
    for (int kk = 0; kk < 2; ++kk) {
      bf16x8 af[4], bfv[4];
      const int c16 = kk * 4 + (lane >> 4);
#pragma unroll
      for (int mi = 0; mi < 4; ++mi) {
        int row = wm * 64 + mi * 16 + (lane & 15);
        af[mi] = __builtin_bit_cast(bf16x8, sh[cur * 1024 + row * 8 + (c16 ^ (row & 7))]);
      }
#pragma unroll
      for (int ni = 0; ni < 4; ++ni) {
        int row = wn * 64 + ni * 16 + (lane & 15);
        bfv[ni] = __builtin_bit_cast(bf16x8, sh[2048 + cur * 1024 + row * 8 + (c16 ^ (row & 7))]);
      }
#pragma unroll
      for (int mi = 0; mi < 4; ++mi)
#pragma unroll
        for (int ni = 0; ni < 4; ++ni)
          acc[mi][ni] = __builtin_amdgcn_mfma_f32_16x16x32_bf16(af[mi], bfv[ni], acc[mi][ni], 0, 0, 0);
    }
    __syncthreads();
    cur ^= 1;
  }

  // phase 1: dump 128x128 f32 C-tile into LDS, chunk-XOR swizzled
  f32x4* cf = reinterpret_cast<f32x4*>(sh);
#pragma unroll
  for (int ni = 0; ni < 4; ++ni) {
    const int c = wn * 64 + ni * 16 + (lane & 15);
#pragma unroll
    for (int mi = 0; mi < 4; ++mi) {
      const int rj = (wm * 64 + mi * 16 + ((lane >> 4) * 4)) >> 2;
      cf[c * 32 + (rj ^ (c & 7))] = acc[mi][ni];
    }
  }
  __syncthreads();
  // phase 2: coalesced stores — 32 lanes sweep rj for a fixed channel c
  const int b = (bm * 128) >> 13;
  const int n0 = (bm * 128) & 8191;
#pragma unroll
  for (int i = 0; i < 16; ++i) {
    const int ch = t + i * 256;            // 0..4095
    const int c = ch >> 5, rj = ch & 31;
    f32x4 v = cf[c * 32 + (rj ^ (c & 7))];
    const int col = bn * 128 + c;
    const float sc = scale[col], shv = shift[col];
    f32x4 o;
    o.x = fmaxf(__builtin_fmaf(v.x, sc, shv), 0.0f);
    o.y = fmaxf(__builtin_fmaf(v.y, sc, shv), 0.0f);
    o.z = fmaxf(__builtin_fmaf(v.z, sc, shv), 0.0f);
    o.w = fmaxf(__builtin_fmaf(v.w, sc, shv), 0.0f);
    *reinterpret_cast<f32x4*>(&outp[(((size_t)b * 256 + col) << 13) + n0 + rj * 4]) = o;
  }
}

extern "C" void kernel_launch(void* const* d_in, const int* in_sizes, int n_in,
                              void* d_out, int out_size, void* d_ws, size_t ws_size,
                              hipStream_t stream) {
  const float* xyz1 = (const float*)d_in[0];
  const float* xyz2 = (const float*)d_in[1];
  const float* points1 = (const float*)d_in[2];
  const float* points2 = (const float*)d_in[3];
  const float* w0 = (const float*)d_in[4];
  const float* b0 = (const float*)d_in[5];
  const float* g0 = (const float*)d_in[6];
  const float* be0 = (const float*)d_in[7];
  const float* m0 = (const float*)d_in[8];
  const float* v0 = (const float*)d_in[9];
  const float* w1 = (const float*)d_in[10];
  const float* b1 = (const float*)d_in[11];
  const float* g1 = (const float*)d_in[12];
  const float* be1 = (const float*)d_in[13];
  const float* m1 = (const float*)d_in[14];
  const float* v1 = (const float*)d_in[15];

  char* ws = (char*)d_ws;
  size_t off = 0;
  auto alloc = [&](size_t bytes) {
    void* p = ws + off;
    off += (bytes + 255) & ~(size_t)255;
    return p;
  };
  unsigned short* Abuf = (unsigned short*)alloc((size_t)MTOT * CIN * 2);   // 32 MB
  unsigned short* Hbuf = (unsigned short*)alloc((size_t)MTOT * 512 * 2);   // 32 MB
  unsigned short* W0T  = (unsigned short*)alloc((size_t)512 * 512 * 2);
  unsigned short* W1T  = (unsigned short*)alloc((size_t)256 * 512 * 2);
  unsigned short* P2T  = (unsigned short*)alloc((size_t)NB * SPTS * DF * 2);
  int*   oidx = (int*)alloc((size_t)MTOT * 3 * 4);
  float* ow   = (float*)alloc((size_t)MTOT * 3 * 4);
  float* sc0 = (float*)alloc(512 * 4);
  float* sh0 = (float*)alloc(512 * 4);
  float* sc1 = (float*)alloc(256 * 4);
  float* sh1 = (float*)alloc(256 * 4);
  (void)ws_size; (void)in_sizes; (void)n_in; (void)out_size;

  preknn_kernel<<<3169, 512, 0, stream>>>(xyz1, xyz2, points1, points2, w0, w1,
                                          Abuf, P2T, W0T, W1T, oidx, ow,
                                          b0, g0, be0, m0, v0,
                                          b1, g1, be1, m1, v1,
                                          sc0, sh0, sc1, sh1);
  interp_kernel<<<MTOT / 8, 256, 0, stream>>>(P2T, oidx, ow, Abuf);
  gemm1_kernel<<<dim3(256), 512, 0, stream>>>(Abuf, W0T, sc0, sh0, Hbuf);
  gemm2_kernel<<<dim3(256 * 2), 256, 0, stream>>>(Hbuf, W1T, sc1, sh1, (float*)d_out, 2);
}

// Round 9
// 93.132 us; speedup vs baseline: 1.1957x; 1.1957x over previous
//
#include <hip/hip_runtime.h>
#include <cstdint>
#include <cstddef>

typedef __attribute__((ext_vector_type(4))) float f32x4;
typedef __attribute__((ext_vector_type(2))) float f32x2;
typedef __bf16 bf16x8 __attribute__((ext_vector_type(8)));
typedef __attribute__((ext_vector_type(4))) unsigned int u32x4;
typedef __attribute__((ext_vector_type(2))) unsigned int u32x2;

#define DEVI __device__ __forceinline__

static constexpr int NB = 4;      // batches
static constexpr int NPTS = 8192; // N query points
static constexpr int SPTS = 2048; // S source points
static constexpr int DF = 256;    // feature dim of points1/points2
static constexpr int CIN = 512;   // concat width = 2*DF = K of GEMM1
static constexpr int MTOT = NB * NPTS; // 32768 rows

DEVI unsigned short f2b(float f) {
  union { float f; unsigned u; } v; v.f = f;
  unsigned r = v.u + 0x7FFFu + ((v.u >> 16) & 1u);
  return (unsigned short)(r >> 16);
}
DEVI float b2f(unsigned short h) {
  union { unsigned u; float f; } v; v.u = ((unsigned)h) << 16;
  return v.f;
}

typedef const __attribute__((address_space(1))) unsigned int* gas_t;
typedef __attribute__((address_space(3))) unsigned int* las_t;
DEVI void gload16(const void* g, void* l) {
  // async global->LDS, 16B per lane; LDS dest = uniform base + lane*16
  __builtin_amdgcn_global_load_lds((gas_t)g, (las_t)l, 16, 0, 0);
}

// ---------------- fused pre + knn: ONE dispatch, independent block roles.
// blocks [0,512): 3-NN FIRST (R8 lesson: knn-first overlaps with transposes;
// knn-last serializes — R7 regressed 45->66µs at 33% occupancy).
// blocks [512,2560): points1 -> Abuf[:,0:256] ; [2560,3072): points2 -> P2T
// [3072,3136): w0 -> W0T ; [3136,3168): w1 -> W1T ; 3168: BN fold
// LDS: 43.5KB union -> 3 blocks/CU.
__global__ __launch_bounds__(512) void preknn_kernel(
    const float* __restrict__ xyz1, const float* __restrict__ xyz2,
    const float* __restrict__ points1, const float* __restrict__ points2,
    const float* __restrict__ w0, const float* __restrict__ w1,
    unsigned short* __restrict__ Abuf, unsigned short* __restrict__ P2T,
    unsigned short* __restrict__ W0T, unsigned short* __restrict__ W1T,
    int* __restrict__ oidx, float* __restrict__ ow,
    const float* __restrict__ b0, const float* __restrict__ g0, const float* __restrict__ be0,
    const float* __restrict__ m0, const float* __restrict__ v0,
    const float* __restrict__ b1, const float* __restrict__ g1, const float* __restrict__ be1,
    const float* __restrict__ m1, const float* __restrict__ v1,
    float* __restrict__ sc0, float* __restrict__ sh0,
    float* __restrict__ sc1, float* __restrict__ sh1) {
  __shared__ __align__(16) char ldsbuf[43520];
  const int bid = blockIdx.x;

  if (bid < 512) {
    // ---- 3-NN, wave-parallel over S, branchless top-3, packed-f32 pairs.
    // LDS: spA[j]={x(2j),x(2j+1),y(2j),y(2j+1)}, spB[j]={z.,z.,|s|^2 pair}
    f32x4* spA = reinterpret_cast<f32x4*>(ldsbuf);                            // 16KB
    f32x4* spB = reinterpret_cast<f32x4*>(ldsbuf + 16384);                    // 16KB
    float (*md)[64][3] = reinterpret_cast<float(*)[64][3]>(ldsbuf + 32768);   // 5376B
    int   (*mi)[64][3] = reinterpret_cast<int(*)[64][3]>(ldsbuf + 38144);     // 5376B
    const int batch = bid >> 7;
    const int nbase = (bid & 127) << 6;
    const float* xb = xyz2 + (size_t)batch * 3 * SPTS;
    // one source-PAIR per thread: float2 loads (coalesced), f32x4 stores
    // (conflict-free stride-16B — R7's scalar writes cost 131K conflicts)
    for (int j = threadIdx.x; j < SPTS / 2; j += 512) {
      f32x2 xx = *reinterpret_cast<const f32x2*>(xb + 2 * j);
      f32x2 yy = *reinterpret_cast<const f32x2*>(xb + SPTS + 2 * j);
      f32x2 zz = *reinterpret_cast<const f32x2*>(xb + 2 * SPTS + 2 * j);
      float w0s = __fadd_rn(__fadd_rn(__fmul_rn(xx.x, xx.x), __fmul_rn(yy.x, yy.x)), __fmul_rn(zz.x, zz.x));
      float w1s = __fadd_rn(__fadd_rn(__fmul_rn(xx.y, xx.y), __fmul_rn(yy.y, yy.y)), __fmul_rn(zz.y, zz.y));
      f32x4 a, b;
      a.x = xx.x; a.y = xx.y; a.z = yy.x; a.w = yy.y;
      b.x = zz.x; b.y = zz.y; b.z = w0s;  b.w = w1s;
      spA[j] = a;
      spB[j] = b;
    }
    __syncthreads();
    const int lane = threadIdx.x & 63, wave = threadIdx.x >> 6;
    const int n = nbase + lane;
    const float* q = xyz1 + (size_t)batch * 3 * NPTS;
    const float x = q[n], y = q[NPTS + n], z = q[2 * NPTS + n];
    const float qa = __fadd_rn(__fadd_rn(__fmul_rn(x, x), __fmul_rn(y, y)), __fmul_rn(z, z));
    const f32x2 xq2 = {x, x}, yq2 = {y, y}, zq2 = {z, z};
    const f32x2 qa2 = {qa, qa}, n2 = {-2.0f, -2.0f};
    float d0 = 3.4e38f, d1 = 3.4e38f, d2 = 3.4e38f;
    int i0 = 0, i1 = 0, i2 = 0;
    const int j0 = wave << 7;   // 128 source-pairs per wave
#pragma unroll 4
    for (int j = j0; j < j0 + 128; ++j) {
      f32x4 a = spA[j];
      f32x4 b = spB[j];
      f32x2 xx = {a.x, a.y}, yy = {a.z, a.w};
      f32x2 zz = {b.x, b.y}, ww = {b.z, b.w};
      f32x2 dot, t, sqp;
      // per half: dot = fma(z,zq, fma(y,yq, mul(x,xq))); t = add(qa,w);
      // sq = fma(-2,dot,t) — byte-identical to the scalar reference chain.
      asm("v_pk_mul_f32 %0, %1, %2" : "=v"(dot) : "v"(xx), "v"(xq2));
      asm("v_pk_fma_f32 %0, %1, %2, %3" : "=v"(dot) : "v"(yy), "v"(yq2), "v"(dot));
      asm("v_pk_fma_f32 %0, %1, %2, %3" : "=v"(dot) : "v"(zz), "v"(zq2), "v"(dot));
      asm("v_pk_add_f32 %0, %1, %2" : "=v"(t) : "v"(qa2), "v"(ww));
      asm("v_pk_fma_f32 %0, %1, %2, %3" : "=v"(sqp) : "v"(n2), "v"(dot), "v"(t));
      {
        const float sq = sqp.x; const int s = 2 * j;
        const bool c0 = sq < d0, c1 = sq < d1, c2 = sq < d2;
        d2 = c1 ? d1 : (c2 ? sq : d2);
        i2 = c1 ? i1 : (c2 ? s : i2);
        d1 = c0 ? d0 : (c1 ? sq : d1);
        i1 = c0 ? i0 : (c1 ? s : i1);
        d0 = c0 ? sq : d0;
        i0 = c0 ? s : i0;
      }
      {
        const float sq = sqp.y; const int s = 2 * j + 1;
        const bool c0 = sq < d0, c1 = sq < d1, c2 = sq < d2;
        d2 = c1 ? d1 : (c2 ? sq : d2);
        i2 = c1 ? i1 : (c2 ? s : i2);
        d1 = c0 ? d0 : (c1 ? sq : d1);
        i1 = c0 ? i0 : (c1 ? s : i1);
        d0 = c0 ? sq : d0;
        i0 = c0 ? s : i0;
      }
    }
    if (wave != 0) {
      md[wave - 1][lane][0] = d0; mi[wave - 1][lane][0] = i0;
      md[wave - 1][lane][1] = d1; mi[wave - 1][lane][1] = i1;
      md[wave - 1][lane][2] = d2; mi[wave - 1][lane][2] = i2;
    }
    __syncthreads();
    if (wave != 0) return;
#pragma unroll
    for (int w = 0; w < 7; ++w) {
#pragma unroll
      for (int j = 0; j < 3; ++j) {
        float sq = md[w][lane][j];
        int si = mi[w][lane][j];
        const bool c0 = sq < d0, c1 = sq < d1, c2 = sq < d2;
        d2 = c1 ? d1 : (c2 ? sq : d2);
        i2 = c1 ? i1 : (c2 ? si : i2);
        d1 = c0 ? d0 : (c1 ? sq : d1);
        i1 = c0 ? i0 : (c1 ? si : i1);
        d0 = c0 ? sq : d0;
        i0 = c0 ? si : i0;
      }
    }
    float w0v = 1.0f / fmaxf(d0, 1e-10f);
    float w1v = 1.0f / fmaxf(d1, 1e-10f);
    float w2v = 1.0f / fmaxf(d2, 1e-10f);
    float sum = __fadd_rn(__fadd_rn(w0v, w1v), w2v);
    const int p = batch * NPTS + n;
    oidx[3 * p + 0] = i0; oidx[3 * p + 1] = i1; oidx[3 * p + 2] = i2;
    ow[3 * p + 0] = w0v / sum; ow[3 * p + 1] = w1v / sum; ow[3 * p + 2] = w2v / sum;
    return;
  }

  if (bid == 3168) {
    // ---- BN param folding
    const int t = threadIdx.x;
    if (t < 512) {
      float s = g0[t] / sqrtf(v0[t] + 1e-3f);
      sc0[t] = s;
      sh0[t] = (b0[t] - m0[t]) * s + be0[t];
    }
    if (t < 256) {
      float s = g1[t] / sqrtf(v1[t] + 1e-3f);
      sc1[t] = s;
      sh1[t] = (b1[t] - m1[t]) * s + be1[t];
    }
    return;
  }

  // ---- tiled transpose + f32->bf16 cast (512 threads: 8 rows/iter)
  float (*tile)[65] = reinterpret_cast<float(*)[65]>(ldsbuf);
  const float* in; unsigned short* out;
  int cols, tpr, ldo, tl;
  if (bid < 2560) {
    const int i1b = bid - 512; const int b = i1b >> 9; tl = i1b & 511;
    in = points1 + (size_t)b * DF * NPTS;
    out = Abuf + (size_t)b * NPTS * CIN;
    cols = NPTS; tpr = 128; ldo = CIN;
  } else if (bid < 3072) {
    const int i2b = bid - 2560; const int b = i2b >> 7; tl = i2b & 127;
    in = points2 + (size_t)b * DF * SPTS;
    out = P2T + (size_t)b * SPTS * DF;
    cols = SPTS; tpr = 32; ldo = DF;
  } else if (bid < 3136) {
    tl = bid - 3072; in = w0; out = W0T; cols = 512; tpr = 8; ldo = 512;
  } else {
    tl = bid - 3136; in = w1; out = W1T; cols = 256; tpr = 4; ldo = 512;
  }
  const int tr = (tl / tpr) * 64, tc = (tl % tpr) * 64;
  const int lx = threadIdx.x & 63, ly = threadIdx.x >> 6;
#pragma unroll
  for (int i = ly; i < 64; i += 8)
    tile[i][lx] = in[(size_t)(tr + i) * cols + tc + lx];
  __syncthreads();
#pragma unroll
  for (int i = ly; i < 64; i += 8)
    out[(size_t)(tc + i) * ldo + tr + lx] = f2b(tile[lx][i]);
}

// ---------------- interpolation: 2 points per wave (32 lanes x 16B per row).
__global__ __launch_bounds__(256) void interp_kernel(
    const unsigned short* __restrict__ p2t, const int* __restrict__ oidx,
    const float* __restrict__ ow, unsigned short* __restrict__ A) {
  const int l = threadIdx.x & 63;
  const int lo = l & 31;
  const int p = blockIdx.x * 8 + ((threadIdx.x >> 6) << 1) + (l >> 5);
  const int b = p >> 13;
  float a[8] = {};
#pragma unroll
  for (int k = 0; k < 3; ++k) {
    const int id = oidx[3 * p + k];
    const float w = ow[3 * p + k];
    const unsigned short* row = p2t + ((size_t)b * SPTS + id) * DF + lo * 8;
    u32x4 v = *reinterpret_cast<const u32x4*>(row);
#pragma unroll
    for (int j = 0; j < 4; ++j) {
      a[2 * j + 0] = __builtin_fmaf(w, b2f((unsigned short)(v[j] & 0xffff)), a[2 * j + 0]);
      a[2 * j + 1] = __builtin_fmaf(w, b2f((unsigned short)(v[j] >> 16)), a[2 * j + 1]);
    }
  }
  u32x4 o;
#pragma unroll
  for (int j = 0; j < 4; ++j)
    o[j] = (unsigned)f2b(a[2 * j + 0]) | ((unsigned)f2b(a[2 * j + 1]) << 16);
  *reinterpret_cast<u32x4*>(A + (size_t)p * CIN + DF + lo * 8) = o;
}

// ---------------- GEMM1: 256x256 tile, BK=64, 8 waves (2Mx4N), acc[8][4].
// H[M,512] = bf16(relu((A[M,512]*W0T^T)*scale+shift)). 2-phase dbuf,
// global_load_lds w16 pre-swizzled source, 128KB LDS.
__global__ __launch_bounds__(512, 2) void gemm1_kernel(
    const unsigned short* __restrict__ Abuf, const unsigned short* __restrict__ BT,
    const float* __restrict__ scale, const float* __restrict__ shift,
    unsigned short* __restrict__ H) {
  __shared__ u32x4 lsA[2][2048];  // 64KB
  __shared__ u32x4 lsB[2][2048];  // 64KB
  const int wg = (blockIdx.x & 7) * (gridDim.x >> 3) + (blockIdx.x >> 3);
  const int bn = wg & 1, bm = wg >> 1;
  const int t = threadIdx.x;
  const int lane = t & 63, wave = t >> 6;
  const int wm = wave >> 2, wn = wave & 3;  // 2 M-slabs(128) x 4 N-slabs(64)
  f32x4 acc[8][4] = {};
  const size_t arow0 = (size_t)bm * 256;
  const size_t brow0 = (size_t)bn * 256;

  auto stage = [&](int buf, int kb) {
    const int kbase = kb * 64;
#pragma unroll
    for (int i = 0; i < 4; ++i) {
      const int c = t + 512 * i;            // chunk 0..2047
      const int row = c >> 3;
      const int k16 = (c & 7) ^ (row & 7);  // inverse-swizzled source
      gload16(Abuf + (arow0 + row) * 512 + kbase + k16 * 8,
              &lsA[buf][512 * i + wave * 64]);
      gload16(BT + (brow0 + row) * 512 + kbase + k16 * 8,
              &lsB[buf][512 * i + wave * 64]);
    }
  };

  stage(0, 0);
  __syncthreads();
  int cur = 0;
  for (int kb = 0; kb < 8; ++kb) {
    if (kb < 7) stage(cur ^ 1, kb + 1);  // async prefetch overlaps compute
#pragma unroll
    for (int kk = 0; kk < 2; ++kk) {
      bf16x8 af[8], bfv[4];
      const int c16 = kk * 4 + (lane >> 4);
#pragma unroll
      for (int mi = 0; mi < 8; ++mi) {
        int row = wm * 128 + mi * 16 + (lane & 15);
        af[mi] = __builtin_bit_cast(bf16x8, lsA[cur][row * 8 + (c16 ^ (row & 7))]);
      }
#pragma unroll
      for (int ni = 0; ni < 4; ++ni) {
        int row = wn * 64 + ni * 16 + (lane & 15);
        bfv[ni] = __builtin_bit_cast(bf16x8, lsB[cur][row * 8 + (c16 ^ (row & 7))]);
      }
#pragma unroll
      for (int mi = 0; mi < 8; ++mi)
#pragma unroll
        for (int ni = 0; ni < 4; ++ni)
          acc[mi][ni] = __builtin_amdgcn_mfma_f32_16x16x32_bf16(af[mi], bfv[ni], acc[mi][ni], 0, 0, 0);
    }
    __syncthreads();
    cur ^= 1;
  }
  const int colb = bn * 256 + wn * 64;
  const int rowb = bm * 256 + wm * 128;
#pragma unroll
  for (int ni = 0; ni < 4; ++ni) {
    const int col = colb + ni * 16 + (lane & 15);
    const float sc = scale[col], shv = shift[col];
#pragma unroll
    for (int mi = 0; mi < 8; ++mi) {
      const int r0 = rowb + mi * 16 + ((lane >> 4) * 4);
#pragma unroll
      for (int j = 0; j < 4; ++j) {
        float v = fmaxf(__builtin_fmaf(acc[mi][ni][j], sc, shv), 0.0f);
        H[(size_t)(r0 + j) * 512 + col] = f2b(v);
      }
    }
  }
}

// ---------------- GEMM2 (128x128, 4 waves, 2-phase dbuf).
// out f32 [B][256][N]: C-tile routed through LDS then coalesced f32x4 stores.
__global__ __launch_bounds__(256) void gemm2_kernel(
    const unsigned short* __restrict__ Abuf, const unsigned short* __restrict__ BT,
    const float* __restrict__ scale, const float* __restrict__ shift,
    float* __restrict__ outp, int gridN) {
  __shared__ u32x4 sh[4096];  // 64KB: [0..2047]=A dbuf, [2048..4095]=B dbuf
  const int wg = (blockIdx.x & 7) * (gridDim.x >> 3) + (blockIdx.x >> 3);
  const int bn = wg % gridN, bm = wg / gridN;
  const int t = threadIdx.x;
  const int lane = t & 63, wave = t >> 6;
  const int wm = wave >> 1, wn = wave & 1;
  f32x4 acc[4][4] = {};
  const size_t arow0 = (size_t)bm * 128;
  const size_t brow0 = (size_t)bn * 128;

  auto stage = [&](int buf, int kb) {
    const int kbase = kb * 64;
#pragma unroll
    for (int i = 0; i < 4; ++i) {
      const int c = wave * 256 + i * 64 + lane;     // chunk index 0..1023
      const int row = c >> 3;
      const int k16 = (c & 7) ^ (row & 7);          // inverse-swizzled source
      gload16(Abuf + (arow0 + row) * 512 + kbase + k16 * 8,
              &sh[buf * 1024 + wave * 256 + i * 64]);
      gload16(BT + (brow0 + row) * 512 + kbase + k16 * 8,
              &sh[2048 + buf * 1024 + wave * 256 + i * 64]);
    }
  };

  stage(0, 0);
  __syncthreads();
  int cur = 0;
  for (int kb = 0; kb < 8; ++kb) {
    if (kb < 7) stage(cur ^ 1, kb + 1);
#pragma unroll
    for (int kk = 0; kk < 2; ++kk) {
      bf16x8 af[4], bfv[4];
      const int c16 = kk * 4 + (lane >> 4);
#pragma unroll
      for (int mi = 0; mi < 4; ++mi) {
        int row = wm * 64 + mi * 16 + (lane & 15);
        af[mi] = __builtin_bit_cast(bf16x8, sh[cur * 1024 + row * 8 + (c16 ^ (row & 7))]);
      }
#pragma unroll
      for (int ni = 0; ni < 4; ++ni) {
        int row = wn * 64 + ni * 16 + (lane & 15);
        bfv[ni] = __builtin_bit_cast(bf16x8, sh[2048 + cur * 1024 + row * 8 + (c16 ^ (row & 7))]);
      }
#pragma unroll
      for (int mi = 0; mi < 4; ++mi)
#pragma unroll
        for (int ni = 0; ni < 4; ++ni)
          acc[mi][ni] = __builtin_amdgcn_mfma_f32_16x16x32_bf16(af[mi], bfv[ni], acc[mi][ni], 0, 0, 0);
    }
    __syncthreads();
    cur ^= 1;
  }

  // phase 1: dump 128x128 f32 C-tile into LDS, chunk-XOR swizzled
  f32x4* cf = reinterpret_cast<f32x4*>(sh);
#pragma unroll
  for (int ni = 0; ni < 4; ++ni) {
    const int c = wn * 64 + ni * 16 + (lane & 15);
#pragma unroll
    for (int mi = 0; mi < 4; ++mi) {
      const int rj = (wm * 64 + mi * 16 + ((lane >> 4) * 4)) >> 2;
      cf[c * 32 + (rj ^ (c & 7))] = acc[mi][ni];
    }
  }
  __syncthreads();
  // phase 2: coalesced stores — 32 lanes sweep rj for a fixed channel c
  const int b = (bm * 128) >> 13;
  const int n0 = (bm * 128) & 8191;
#pragma unroll
  for (int i = 0; i < 16; ++i) {
    const int ch = t + i * 256;            // 0..4095
    const int c = ch >> 5, rj = ch & 31;
    f32x4 v = cf[c * 32 + (rj ^ (c & 7))];
    const int col = bn * 128 + c;
    const float sc = scale[col], shv = shift[col];
    f32x4 o;
    o.x = fmaxf(__builtin_fmaf(v.x, sc, shv), 0.0f);
    o.y = fmaxf(__builtin_fmaf(v.y, sc, shv), 0.0f);
    o.z = fmaxf(__builtin_fmaf(v.z, sc, shv), 0.0f);
    o.w = fmaxf(__builtin_fmaf(v.w, sc, shv), 0.0f);
    *reinterpret_cast<f32x4*>(&outp[(((size_t)b * 256 + col) << 13) + n0 + rj * 4]) = o;
  }
}

extern "C" void kernel_launch(void* const* d_in, const int* in_sizes, int n_in,
                              void* d_out, int out_size, void* d_ws, size_t ws_size,
                              hipStream_t stream) {
  const float* xyz1 = (const float*)d_in[0];
  const float* xyz2 = (const float*)d_in[1];
  const float* points1 = (const float*)d_in[2];
  const float* points2 = (const float*)d_in[3];
  const float* w0 = (const float*)d_in[4];
  const float* b0 = (const float*)d_in[5];
  const float* g0 = (const float*)d_in[6];
  const float* be0 = (const float*)d_in[7];
  const float* m0 = (const float*)d_in[8];
  const float* v0 = (const float*)d_in[9];
  const float* w1 = (const float*)d_in[10];
  const float* b1 = (const float*)d_in[11];
  const float* g1 = (const float*)d_in[12];
  const float* be1 = (const float*)d_in[13];
  const float* m1 = (const float*)d_in[14];
  const float* v1 = (const float*)d_in[15];

  char* ws = (char*)d_ws;
  size_t off = 0;
  auto alloc = [&](size_t bytes) {
    void* p = ws + off;
    off += (bytes + 255) & ~(size_t)255;
    return p;
  };
  unsigned short* Abuf = (unsigned short*)alloc((size_t)MTOT * CIN * 2);   // 32 MB
  unsigned short* Hbuf = (unsigned short*)alloc((size_t)MTOT * 512 * 2);   // 32 MB
  unsigned short* W0T  = (unsigned short*)alloc((size_t)512 * 512 * 2);
  unsigned short* W1T  = (unsigned short*)alloc((size_t)256 * 512 * 2);
  unsigned short* P2T  = (unsigned short*)alloc((size_t)NB * SPTS * DF * 2);
  int*   oidx = (int*)alloc((size_t)MTOT * 3 * 4);
  float* ow   = (float*)alloc((size_t)MTOT * 3 * 4);
  float* sc0 = (float*)alloc(512 * 4);
  float* sh0 = (float*)alloc(512 * 4);
  float* sc1 = (float*)alloc(256 * 4);
  float* sh1 = (float*)alloc(256 * 4);
  (void)ws_size; (void)in_sizes; (void)n_in; (void)out_size;

  preknn_kernel<<<3169, 512, 0, stream>>>(xyz1, xyz2, points1, points2, w0, w1,
                                          Abuf, P2T, W0T, W1T, oidx, ow,
                                          b0, g0, be0, m0, v0,
                                          b1, g1, be1, m1, v1,
                                          sc0, sh0, sc1, sh1);
  interp_kernel<<<MTOT / 8, 256, 0, stream>>>(P2T, oidx, ow, Abuf);
  gemm1_kernel<<<dim3(256), 512, 0, stream>>>(Abuf, W0T, sc0, sh0, Hbuf);
  gemm2_kernel<<<dim3(256 * 2), 256, 0, stream>>>(Hbuf, W1T, sc1, sh1, (float*)d_out, 2);
}

// Round 10
// 87.748 us; speedup vs baseline: 1.2690x; 1.0614x over previous
//
#include <hip/hip_runtime.h>
#include <cstdint>
#include <cstddef>

typedef __attribute__((ext_vector_type(4))) float f32x4;
typedef __bf16 bf16x8 __attribute__((ext_vector_type(8)));
typedef __attribute__((ext_vector_type(4))) unsigned int u32x4;
typedef __attribute__((ext_vector_type(2))) unsigned int u32x2;

#define DEVI __device__ __forceinline__

static constexpr int NB = 4;      // batches
static constexpr int NPTS = 8192; // N query points
static constexpr int SPTS = 2048; // S source points
static constexpr int DF = 256;    // feature dim of points1/points2
static constexpr int CIN = 512;   // concat width = 2*DF = K of GEMM1
static constexpr int MTOT = NB * NPTS; // 32768 rows

DEVI unsigned short f2b(float f) {
  union { float f; unsigned u; } v; v.f = f;
  unsigned r = v.u + 0x7FFFu + ((v.u >> 16) & 1u);
  return (unsigned short)(r >> 16);
}
DEVI float b2f(unsigned short h) {
  union { unsigned u; float f; } v; v.u = ((unsigned)h) << 16;
  return v.f;
}

typedef const __attribute__((address_space(1))) unsigned int* gas_t;
typedef __attribute__((address_space(3))) unsigned int* las_t;
DEVI void gload16(const void* g, void* l) {
  // async global->LDS, 16B per lane; LDS dest = uniform base + lane*16
  __builtin_amdgcn_global_load_lds((gas_t)g, (las_t)l, 16, 0, 0);
}

// branchless sorted-insert, identical predicates to the serial reference scan
#define KNN_INSERT(sq, s, d0, d1, d2, i0, i1, i2)            \
  {                                                          \
    const bool c0 = (sq) < d0, c1 = (sq) < d1, c2 = (sq) < d2; \
    d2 = c1 ? d1 : (c2 ? (sq) : d2);                         \
    i2 = c1 ? i1 : (c2 ? (s) : i2);                          \
    d1 = c0 ? d0 : (c1 ? (sq) : d1);                         \
    i1 = c0 ? i0 : (c1 ? (s) : i1);                          \
    d0 = c0 ? (sq) : d0;                                     \
    i0 = c0 ? (s) : i0;                                      \
  }

// ---------------- fused pre + knn: ONE dispatch, independent block roles.
// blocks [0,512): 3-NN FIRST (proven: knn-first overlaps with transposes;
// knn-last serialized — R7 45->66µs). blocks [512,2560): points1 -> Abuf;
// [2560,3072): points2 -> P2T; [3072,3136): w0; [3136,3168): w1; 3168: BN.
// LDS: 43.5KB union -> 3 blocks/CU.
__global__ __launch_bounds__(512) void preknn_kernel(
    const float* __restrict__ xyz1, const float* __restrict__ xyz2,
    const float* __restrict__ points1, const float* __restrict__ points2,
    const float* __restrict__ w0, const float* __restrict__ w1,
    unsigned short* __restrict__ Abuf, unsigned short* __restrict__ P2T,
    unsigned short* __restrict__ W0T, unsigned short* __restrict__ W1T,
    int* __restrict__ oidx, float* __restrict__ ow,
    const float* __restrict__ b0, const float* __restrict__ g0, const float* __restrict__ be0,
    const float* __restrict__ m0, const float* __restrict__ v0,
    const float* __restrict__ b1, const float* __restrict__ g1, const float* __restrict__ be1,
    const float* __restrict__ m1, const float* __restrict__ v1,
    float* __restrict__ sc0, float* __restrict__ sh0,
    float* __restrict__ sc1, float* __restrict__ sh1) {
  __shared__ __align__(16) char ldsbuf[43520];
  const int bid = blockIdx.x;

  if (bid < 512) {
    // ---- 3-NN, wave-parallel over S, branchless top-3, 2-stream ILP.
    // R9 lesson: kernel is dep-stall-bound, not issue-bound (pk cut issued
    // work 10% yet slowed 12%). Two independent scan states per lane halve
    // the serial select-chain depth; scalar arithmetic is byte-identical to
    // the reference. B-stream merge = same strict-< ascending-index insert
    // proven for the cross-wave merge.
    f32x4* sp = reinterpret_cast<f32x4*>(ldsbuf);                            // 32KB
    float (*md)[64][3] = reinterpret_cast<float(*)[64][3]>(ldsbuf + 32768);  // 5376B
    int   (*mi)[64][3] = reinterpret_cast<int(*)[64][3]>(ldsbuf + 38144);    // 5376B
    const int batch = bid >> 7;
    const int nbase = (bid & 127) << 6;
    const float* xb = xyz2 + (size_t)batch * 3 * SPTS;
    for (int i = threadIdx.x; i < SPTS; i += 512) {
      float a = xb[i], b = xb[SPTS + i], c = xb[2 * SPTS + i];
      f32x4 v;
      v.x = a; v.y = b; v.z = c;
      v.w = __fadd_rn(__fadd_rn(__fmul_rn(a, a), __fmul_rn(b, b)), __fmul_rn(c, c));
      sp[i] = v;
    }
    __syncthreads();
    const int lane = threadIdx.x & 63, wave = threadIdx.x >> 6;
    const int n = nbase + lane;
    const float* q = xyz1 + (size_t)batch * 3 * NPTS;
    const float x = q[n], y = q[NPTS + n], z = q[2 * NPTS + n];
    const float qa = __fadd_rn(__fadd_rn(__fmul_rn(x, x), __fmul_rn(y, y)), __fmul_rn(z, z));
    float d0 = 3.4e38f, d1 = 3.4e38f, d2 = 3.4e38f;
    int i0 = 0, i1 = 0, i2 = 0;
    float e0 = 3.4e38f, e1 = 3.4e38f, e2 = 3.4e38f;
    int j0i = 0, j1i = 0, j2i = 0;
    const int s0 = wave << 8;
#pragma unroll 4
    for (int k = 0; k < 128; ++k) {
      f32x4 va = sp[s0 + k];
      f32x4 vb = sp[s0 + 128 + k];
      float dota = __builtin_fmaf(va.z, z, __builtin_fmaf(va.y, y, __fmul_rn(va.x, x)));
      float dotb = __builtin_fmaf(vb.z, z, __builtin_fmaf(vb.y, y, __fmul_rn(vb.x, x)));
      // 2*dot exact => fma(-2,dot,t) == fsub(t, fmul(2,dot)) bit-exactly
      float sqa = __builtin_fmaf(-2.0f, dota, __fadd_rn(qa, va.w));
      float sqb = __builtin_fmaf(-2.0f, dotb, __fadd_rn(qa, vb.w));
      const int sa = s0 + k, sb = s0 + 128 + k;
      KNN_INSERT(sqa, sa, d0, d1, d2, i0, i1, i2);
      KNN_INSERT(sqb, sb, e0, e1, e2, j0i, j1i, j2i);
    }
    // merge stream B into A (ascending distance order; all B idx > A idx)
    KNN_INSERT(e0, j0i, d0, d1, d2, i0, i1, i2);
    KNN_INSERT(e1, j1i, d0, d1, d2, i0, i1, i2);
    KNN_INSERT(e2, j2i, d0, d1, d2, i0, i1, i2);
    if (wave != 0) {
      md[wave - 1][lane][0] = d0; mi[wave - 1][lane][0] = i0;
      md[wave - 1][lane][1] = d1; mi[wave - 1][lane][1] = i1;
      md[wave - 1][lane][2] = d2; mi[wave - 1][lane][2] = i2;
    }
    __syncthreads();
    if (wave != 0) return;
#pragma unroll
    for (int w = 0; w < 7; ++w) {
#pragma unroll
      for (int j = 0; j < 3; ++j) {
        float sq = md[w][lane][j];
        int si = mi[w][lane][j];
        KNN_INSERT(sq, si, d0, d1, d2, i0, i1, i2);
      }
    }
    float w0v = 1.0f / fmaxf(d0, 1e-10f);
    float w1v = 1.0f / fmaxf(d1, 1e-10f);
    float w2v = 1.0f / fmaxf(d2, 1e-10f);
    float sum = __fadd_rn(__fadd_rn(w0v, w1v), w2v);
    const int p = batch * NPTS + n;
    oidx[3 * p + 0] = i0; oidx[3 * p + 1] = i1; oidx[3 * p + 2] = i2;
    ow[3 * p + 0] = w0v / sum; ow[3 * p + 1] = w1v / sum; ow[3 * p + 2] = w2v / sum;
    return;
  }

  if (bid == 3168) {
    // ---- BN param folding
    const int t = threadIdx.x;
    if (t < 512) {
      float s = g0[t] / sqrtf(v0[t] + 1e-3f);
      sc0[t] = s;
      sh0[t] = (b0[t] - m0[t]) * s + be0[t];
    }
    if (t < 256) {
      float s = g1[t] / sqrtf(v1[t] + 1e-3f);
      sc1[t] = s;
      sh1[t] = (b1[t] - m1[t]) * s + be1[t];
    }
    return;
  }

  // ---- tiled transpose + f32->bf16 cast (512 threads: 8 rows/iter)
  float (*tile)[65] = reinterpret_cast<float(*)[65]>(ldsbuf);
  const float* in; unsigned short* out;
  int cols, tpr, ldo, tl;
  if (bid < 2560) {
    const int i1b = bid - 512; const int b = i1b >> 9; tl = i1b & 511;
    in = points1 + (size_t)b * DF * NPTS;
    out = Abuf + (size_t)b * NPTS * CIN;
    cols = NPTS; tpr = 128; ldo = CIN;
  } else if (bid < 3072) {
    const int i2b = bid - 2560; const int b = i2b >> 7; tl = i2b & 127;
    in = points2 + (size_t)b * DF * SPTS;
    out = P2T + (size_t)b * SPTS * DF;
    cols = SPTS; tpr = 32; ldo = DF;
  } else if (bid < 3136) {
    tl = bid - 3072; in = w0; out = W0T; cols = 512; tpr = 8; ldo = 512;
  } else {
    tl = bid - 3136; in = w1; out = W1T; cols = 256; tpr = 4; ldo = 512;
  }
  const int tr = (tl / tpr) * 64, tc = (tl % tpr) * 64;
  const int lx = threadIdx.x & 63, ly = threadIdx.x >> 6;
#pragma unroll
  for (int i = ly; i < 64; i += 8)
    tile[i][lx] = in[(size_t)(tr + i) * cols + tc + lx];
  __syncthreads();
#pragma unroll
  for (int i = ly; i < 64; i += 8)
    out[(size_t)(tc + i) * ldo + tr + lx] = f2b(tile[lx][i]);
}

// ---------------- interpolation: 2 points per wave (32 lanes x 16B per row).
__global__ __launch_bounds__(256) void interp_kernel(
    const unsigned short* __restrict__ p2t, const int* __restrict__ oidx,
    const float* __restrict__ ow, unsigned short* __restrict__ A) {
  const int l = threadIdx.x & 63;
  const int lo = l & 31;
  const int p = blockIdx.x * 8 + ((threadIdx.x >> 6) << 1) + (l >> 5);
  const int b = p >> 13;
  float a[8] = {};
#pragma unroll
  for (int k = 0; k < 3; ++k) {
    const int id = oidx[3 * p + k];
    const float w = ow[3 * p + k];
    const unsigned short* row = p2t + ((size_t)b * SPTS + id) * DF + lo * 8;
    u32x4 v = *reinterpret_cast<const u32x4*>(row);
#pragma unroll
    for (int j = 0; j < 4; ++j) {
      a[2 * j + 0] = __builtin_fmaf(w, b2f((unsigned short)(v[j] & 0xffff)), a[2 * j + 0]);
      a[2 * j + 1] = __builtin_fmaf(w, b2f((unsigned short)(v[j] >> 16)), a[2 * j + 1]);
    }
  }
  u32x4 o;
#pragma unroll
  for (int j = 0; j < 4; ++j)
    o[j] = (unsigned)f2b(a[2 * j + 0]) | ((unsigned)f2b(a[2 * j + 1]) << 16);
  *reinterpret_cast<u32x4*>(A + (size_t)p * CIN + DF + lo * 8) = o;
}

// ---------------- GEMM1: 256x256 tile, BK=64, 8 waves (2Mx4N), acc[8][4].
// H[M,512] = bf16(relu((A[M,512]*W0T^T)*scale+shift)). 2-phase dbuf,
// global_load_lds w16 pre-swizzled source, 128KB LDS.
__global__ __launch_bounds__(512, 2) void gemm1_kernel(
    const unsigned short* __restrict__ Abuf, const unsigned short* __restrict__ BT,
    const float* __restrict__ scale, const float* __restrict__ shift,
    unsigned short* __restrict__ H) {
  __shared__ u32x4 lsA[2][2048];  // 64KB
  __shared__ u32x4 lsB[2][2048];  // 64KB
  const int wg = (blockIdx.x & 7) * (gridDim.x >> 3) + (blockIdx.x >> 3);
  const int bn = wg & 1, bm = wg >> 1;
  const int t = threadIdx.x;
  const int lane = t & 63, wave = t >> 6;
  const int wm = wave >> 2, wn = wave & 3;  // 2 M-slabs(128) x 4 N-slabs(64)
  f32x4 acc[8][4] = {};
  const size_t arow0 = (size_t)bm * 256;
  const size_t brow0 = (size_t)bn * 256;

  auto stage = [&](int buf, int kb) {
    const int kbase = kb * 64;
#pragma unroll
    for (int i = 0; i < 4; ++i) {
      const int c = t + 512 * i;            // chunk 0..2047
      const int row = c >> 3;
      const int k16 = (c & 7) ^ (row & 7);  // inverse-swizzled source
      gload16(Abuf + (arow0 + row) * 512 + kbase + k16 * 8,
              &lsA[buf][512 * i + wave * 64]);
      gload16(BT + (brow0 + row) * 512 + kbase + k16 * 8,
              &lsB[buf][512 * i + wave * 64]);
    }
  };

  stage(0, 0);
  __syncthreads();
  int cur = 0;
  for (int kb = 0; kb < 8; ++kb) {
    if (kb < 7) stage(cur ^ 1, kb + 1);  // async prefetch overlaps compute
#pragma unroll
    for (int kk = 0; kk < 2; ++kk) {
      bf16x8 af[8], bfv[4];
      const int c16 = kk * 4 + (lane >> 4);
#pragma unroll
      for (int mi = 0; mi < 8; ++mi) {
        int row = wm * 128 + mi * 16 + (lane & 15);
        af[mi] = __builtin_bit_cast(bf16x8, lsA[cur][row * 8 + (c16 ^ (row & 7))]);
      }
#pragma unroll
      for (int ni = 0; ni < 4; ++ni) {
        int row = wn * 64 + ni * 16 + (lane & 15);
        bfv[ni] = __builtin_bit_cast(bf16x8, lsB[cur][row * 8 + (c16 ^ (row & 7))]);
      }
#pragma unroll
      for (int mi = 0; mi < 8; ++mi)
#pragma unroll
        for (int ni = 0; ni < 4; ++ni)
          acc[mi][ni] = __builtin_amdgcn_mfma_f32_16x16x32_bf16(af[mi], bfv[ni], acc[mi][ni], 0, 0, 0);
    }
    __syncthreads();
    cur ^= 1;
  }
  const int colb = bn * 256 + wn * 64;
  const int rowb = bm * 256 + wm * 128;
#pragma unroll
  for (int ni = 0; ni < 4; ++ni) {
    const int col = colb + ni * 16 + (lane & 15);
    const float sc = scale[col], shv = shift[col];
#pragma unroll
    for (int mi = 0; mi < 8; ++mi) {
      const int r0 = rowb + mi * 16 + ((lane >> 4) * 4);
#pragma unroll
      for (int j = 0; j < 4; ++j) {
        float v = fmaxf(__builtin_fmaf(acc[mi][ni][j], sc, shv), 0.0f);
        H[(size_t)(r0 + j) * 512 + col] = f2b(v);
      }
    }
  }
}

// ---------------- GEMM2 (128x128, 4 waves, 2-phase dbuf).
// out f32 [B][256][N]: C-tile routed through LDS then coalesced f32x4 stores.
__global__ __launch_bounds__(256) void gemm2_kernel(
    const unsigned short* __restrict__ Abuf, const unsigned short* __restrict__ BT,
    const float* __restrict__ scale, const float* __restrict__ shift,
    float* __restrict__ outp, int gridN) {
  __shared__ u32x4 sh[4096];  // 64KB: [0..2047]=A dbuf, [2048..4095]=B dbuf
  const int wg = (blockIdx.x & 7) * (gridDim.x >> 3) + (blockIdx.x >> 3);
  const int bn = wg % gridN, bm = wg / gridN;
  const int t = threadIdx.x;
  const int lane = t & 63, wave = t >> 6;
  const int wm = wave >> 1, wn = wave & 1;
  f32x4 acc[4][4] = {};
  const size_t arow0 = (size_t)bm * 128;
  const size_t brow0 = (size_t)bn * 128;

  auto stage = [&](int buf, int kb) {
    const int kbase = kb * 64;
#pragma unroll
    for (int i = 0; i < 4; ++i) {
      const int c = wave * 256 + i * 64 + lane;     // chunk index 0..1023
      const int row = c >> 3;
      const int k16 = (c & 7) ^ (row & 7);          // inverse-swizzled source
      gload16(Abuf + (arow0 + row) * 512 + kbase + k16 * 8,
              &sh[buf * 1024 + wave * 256 + i * 64]);
      gload16(BT + (brow0 + row) * 512 + kbase + k16 * 8,
              &sh[2048 + buf * 1024 + wave * 256 + i * 64]);
    }
  };

  stage(0, 0);
  __syncthreads();
  int cur = 0;
  for (int kb = 0; kb < 8; ++kb) {
    if (kb < 7) stage(cur ^ 1, kb + 1);
#pragma unroll
    for (int kk = 0; kk < 2; ++kk) {
      bf16x8 af[4], bfv[4];
      const int c16 = kk * 4 + (lane >> 4);
#pragma unroll
      for (int mi = 0; mi < 4; ++mi) {
        int row = wm * 64 + mi * 16 + (lane & 15);
        af[mi] = __builtin_bit_cast(bf16x8, sh[cur * 1024 + row * 8 + (c16 ^ (row & 7))]);
      }
#pragma unroll
      for (int ni = 0; ni < 4; ++ni) {
        int row = wn * 64 + ni * 16 + (lane & 15);
        bfv[ni] = __builtin_bit_cast(bf16x8, sh[2048 + cur * 1024 + row * 8 + (c16 ^ (row & 7))]);
      }
#pragma unroll
      for (int mi = 0; mi < 4; ++mi)
#pragma unroll
        for (int ni = 0; ni < 4; ++ni)
          acc[mi][ni] = __builtin_amdgcn_mfma_f32_16x16x32_bf16(af[mi], bfv[ni], acc[mi][ni], 0, 0, 0);
    }
    __syncthreads();
    cur ^= 1;
  }

  // phase 1: dump 128x128 f32 C-tile into LDS, chunk-XOR swizzled
  f32x4* cf = reinterpret_cast<f32x4*>(sh);
#pragma unroll
  for (int ni = 0; ni < 4; ++ni) {
    const int c = wn * 64 + ni * 16 + (lane & 15);
#pragma unroll
    for (int mi = 0; mi < 4; ++mi) {
      const int rj = (wm * 64 + mi * 16 + ((lane >> 4) * 4)) >> 2;
      cf[c * 32 + (rj ^ (c & 7))] = acc[mi][ni];
    }
  }
  __syncthreads();
  // phase 2: coalesced stores — 32 lanes sweep rj for a fixed channel c
  const int b = (bm * 128) >> 13;
  const int n0 = (bm * 128) & 8191;
#pragma unroll
  for (int i = 0; i < 16; ++i) {
    const int ch = t + i * 256;            // 0..4095
    const int c = ch >> 5, rj = ch & 31;
    f32x4 v = cf[c * 32 + (rj ^ (c & 7))];
    const int col = bn * 128 + c;
    const float sc = scale[col], shv = shift[col];
    f32x4 o;
    o.x = fmaxf(__builtin_fmaf(v.x, sc, shv), 0.0f);
    o.y = fmaxf(__builtin_fmaf(v.y, sc, shv), 0.0f);
    o.z = fmaxf(__builtin_fmaf(v.z, sc, shv), 0.0f);
    o.w = fmaxf(__builtin_fmaf(v.w, sc, shv), 0.0f);
    *reinterpret_cast<f32x4*>(&outp[(((size_t)b * 256 + col) << 13) + n0 + rj * 4]) = o;
  }
}

extern "C" void kernel_launch(void* const* d_in, const int* in_sizes, int n_in,
                              void* d_out, int out_size, void* d_ws, size_t ws_size,
                              hipStream_t stream) {
  const float* xyz1 = (const float*)d_in[0];
  const float* xyz2 = (const float*)d_in[1];
  const float* points1 = (const float*)d_in[2];
  const float* points2 = (const float*)d_in[3];
  const float* w0 = (const float*)d_in[4];
  const float* b0 = (const float*)d_in[5];
  const float* g0 = (const float*)d_in[6];
  const float* be0 = (const float*)d_in[7];
  const float* m0 = (const float*)d_in[8];
  const float* v0 = (const float*)d_in[9];
  const float* w1 = (const float*)d_in[10];
  const float* b1 = (const float*)d_in[11];
  const float* g1 = (const float*)d_in[12];
  const float* be1 = (const float*)d_in[13];
  const float* m1 = (const float*)d_in[14];
  const float* v1 = (const float*)d_in[15];

  char* ws = (char*)d_ws;
  size_t off = 0;
  auto alloc = [&](size_t bytes) {
    void* p = ws + off;
    off += (bytes + 255) & ~(size_t)255;
    return p;
  };
  unsigned short* Abuf = (unsigned short*)alloc((size_t)MTOT * CIN * 2);   // 32 MB
  unsigned short* Hbuf = (unsigned short*)alloc((size_t)MTOT * 512 * 2);   // 32 MB
  unsigned short* W0T  = (unsigned short*)alloc((size_t)512 * 512 * 2);
  unsigned short* W1T  = (unsigned short*)alloc((size_t)256 * 512 * 2);
  unsigned short* P2T  = (unsigned short*)alloc((size_t)NB * SPTS * DF * 2);
  int*   oidx = (int*)alloc((size_t)MTOT * 3 * 4);
  float* ow   = (float*)alloc((size_t)MTOT * 3 * 4);
  float* sc0 = (float*)alloc(512 * 4);
  float* sh0 = (float*)alloc(512 * 4);
  float* sc1 = (float*)alloc(256 * 4);
  float* sh1 = (float*)alloc(256 * 4);
  (void)ws_size; (void)in_sizes; (void)n_in; (void)out_size;

  preknn_kernel<<<3169, 512, 0, stream>>>(xyz1, xyz2, points1, points2, w0, w1,
                                          Abuf, P2T, W0T, W1T, oidx, ow,
                                          b0, g0, be0, m0, v0,
                                          b1, g1, be1, m1, v1,
                                          sc0, sh0, sc1, sh1);
  interp_kernel<<<MTOT / 8, 256, 0, stream>>>(P2T, oidx, ow, Abuf);
  gemm1_kernel<<<dim3(256), 512, 0, stream>>>(Abuf, W0T, sc0, sh0, Hbuf);
  gemm2_kernel<<<dim3(256 * 2), 256, 0, stream>>>(Hbuf, W1T, sc1, sh1, (float*)d_out, 2);
}

// Round 11
// 86.510 us; speedup vs baseline: 1.2872x; 1.0143x over previous
//
#include <hip/hip_runtime.h>
#include <cstdint>
#include <cstddef>

typedef __attribute__((ext_vector_type(4))) float f32x4;
typedef __bf16 bf16x8 __attribute__((ext_vector_type(8)));
typedef __attribute__((ext_vector_type(4))) unsigned int u32x4;
typedef __attribute__((ext_vector_type(2))) unsigned int u32x2;

#define DEVI __device__ __forceinline__

static constexpr int NB = 4;      // batches
static constexpr int NPTS = 8192; // N query points
static constexpr int SPTS = 2048; // S source points
static constexpr int DF = 256;    // feature dim of points1/points2
static constexpr int CIN = 512;   // concat width = 2*DF = K of GEMM1
static constexpr int MTOT = NB * NPTS; // 32768 rows

DEVI unsigned short f2b(float f) {
  union { float f; unsigned u; } v; v.f = f;
  unsigned r = v.u + 0x7FFFu + ((v.u >> 16) & 1u);
  return (unsigned short)(r >> 16);
}
DEVI float b2f(unsigned short h) {
  union { unsigned u; float f; } v; v.u = ((unsigned)h) << 16;
  return v.f;
}

typedef const __attribute__((address_space(1))) unsigned int* gas_t;
typedef __attribute__((address_space(3))) unsigned int* las_t;
DEVI void gload16(const void* g, void* l) {
  // async global->LDS, 16B per lane; LDS dest = uniform base + lane*16
  __builtin_amdgcn_global_load_lds((gas_t)g, (las_t)l, 16, 0, 0);
}

// branchless sorted-insert, identical predicates to the serial reference scan
#define KNN_INSERT(sq, s, d0, d1, d2, i0, i1, i2)            \
  {                                                          \
    const bool c0 = (sq) < d0, c1 = (sq) < d1, c2 = (sq) < d2; \
    d2 = c1 ? d1 : (c2 ? (sq) : d2);                         \
    i2 = c1 ? i1 : (c2 ? (s) : i2);                          \
    d1 = c0 ? d0 : (c1 ? (sq) : d1);                         \
    i1 = c0 ? i0 : (c1 ? (s) : i1);                          \
    d0 = c0 ? (sq) : d0;                                     \
    i0 = c0 ? (s) : i0;                                      \
  }

// ---------------- fused pre + knn: ONE dispatch, independent block roles.
// blocks [0,512): 3-NN FIRST (proven: knn-first overlaps with transposes).
// blocks [512,2560): points1 -> Abuf; [2560,3072): points2 -> P2T;
// [3072,3136): w0; [3136,3168): w1; 3168: BN fold.
// LDS: 32KB (R10: merge buffers REUSE sp's space behind a barrier —
// 43.5KB->32.8KB lifts capacity 3->4 blocks/CU; knn occupancy was the cap).
__global__ __launch_bounds__(512) void preknn_kernel(
    const float* __restrict__ xyz1, const float* __restrict__ xyz2,
    const float* __restrict__ points1, const float* __restrict__ points2,
    const float* __restrict__ w0, const float* __restrict__ w1,
    unsigned short* __restrict__ Abuf, unsigned short* __restrict__ P2T,
    unsigned short* __restrict__ W0T, unsigned short* __restrict__ W1T,
    int* __restrict__ oidx, float* __restrict__ ow,
    const float* __restrict__ b0, const float* __restrict__ g0, const float* __restrict__ be0,
    const float* __restrict__ m0, const float* __restrict__ v0,
    const float* __restrict__ b1, const float* __restrict__ g1, const float* __restrict__ be1,
    const float* __restrict__ m1, const float* __restrict__ v1,
    float* __restrict__ sc0, float* __restrict__ sh0,
    float* __restrict__ sc1, float* __restrict__ sh1) {
  __shared__ __align__(16) char ldsbuf[32768];
  const int bid = blockIdx.x;

  if (bid < 512) {
    // ---- 3-NN, wave-parallel over S, branchless top-3, 2-stream ILP.
    f32x4* sp = reinterpret_cast<f32x4*>(ldsbuf);                      // 32KB
    // merge buffers OVERLAY sp — only touched after the post-scan barrier
    float (*md)[64][3] = reinterpret_cast<float(*)[64][3]>(ldsbuf);         // 5376B
    int   (*mi)[64][3] = reinterpret_cast<int(*)[64][3]>(ldsbuf + 5376);    // 5376B
    const int batch = bid >> 7;
    const int nbase = (bid & 127) << 6;
    const float* xb = xyz2 + (size_t)batch * 3 * SPTS;
    for (int i = threadIdx.x; i < SPTS; i += 512) {
      float a = xb[i], b = xb[SPTS + i], c = xb[2 * SPTS + i];
      f32x4 v;
      v.x = a; v.y = b; v.z = c;
      v.w = __fadd_rn(__fadd_rn(__fmul_rn(a, a), __fmul_rn(b, b)), __fmul_rn(c, c));
      sp[i] = v;
    }
    __syncthreads();
    const int lane = threadIdx.x & 63, wave = threadIdx.x >> 6;
    const int n = nbase + lane;
    const float* q = xyz1 + (size_t)batch * 3 * NPTS;
    const float x = q[n], y = q[NPTS + n], z = q[2 * NPTS + n];
    const float qa = __fadd_rn(__fadd_rn(__fmul_rn(x, x), __fmul_rn(y, y)), __fmul_rn(z, z));
    float d0 = 3.4e38f, d1 = 3.4e38f, d2 = 3.4e38f;
    int i0 = 0, i1 = 0, i2 = 0;
    float e0 = 3.4e38f, e1 = 3.4e38f, e2 = 3.4e38f;
    int j0i = 0, j1i = 0, j2i = 0;
    const int s0 = wave << 8;
#pragma unroll 4
    for (int k = 0; k < 128; ++k) {
      f32x4 va = sp[s0 + k];
      f32x4 vb = sp[s0 + 128 + k];
      float dota = __builtin_fmaf(va.z, z, __builtin_fmaf(va.y, y, __fmul_rn(va.x, x)));
      float dotb = __builtin_fmaf(vb.z, z, __builtin_fmaf(vb.y, y, __fmul_rn(vb.x, x)));
      // 2*dot exact => fma(-2,dot,t) == fsub(t, fmul(2,dot)) bit-exactly
      float sqa = __builtin_fmaf(-2.0f, dota, __fadd_rn(qa, va.w));
      float sqb = __builtin_fmaf(-2.0f, dotb, __fadd_rn(qa, vb.w));
      const int sa = s0 + k, sb = s0 + 128 + k;
      KNN_INSERT(sqa, sa, d0, d1, d2, i0, i1, i2);
      KNN_INSERT(sqb, sb, e0, e1, e2, j0i, j1i, j2i);
    }
    // merge stream B into A (ascending distance order; all B idx > A idx)
    KNN_INSERT(e0, j0i, d0, d1, d2, i0, i1, i2);
    KNN_INSERT(e1, j1i, d0, d1, d2, i0, i1, i2);
    KNN_INSERT(e2, j2i, d0, d1, d2, i0, i1, i2);
    __syncthreads();  // all sp reads complete — safe to overlay md/mi
    if (wave != 0) {
      md[wave - 1][lane][0] = d0; mi[wave - 1][lane][0] = i0;
      md[wave - 1][lane][1] = d1; mi[wave - 1][lane][1] = i1;
      md[wave - 1][lane][2] = d2; mi[wave - 1][lane][2] = i2;
    }
    __syncthreads();
    if (wave != 0) return;
#pragma unroll
    for (int w = 0; w < 7; ++w) {
#pragma unroll
      for (int j = 0; j < 3; ++j) {
        float sq = md[w][lane][j];
        int si = mi[w][lane][j];
        KNN_INSERT(sq, si, d0, d1, d2, i0, i1, i2);
      }
    }
    float w0v = 1.0f / fmaxf(d0, 1e-10f);
    float w1v = 1.0f / fmaxf(d1, 1e-10f);
    float w2v = 1.0f / fmaxf(d2, 1e-10f);
    float sum = __fadd_rn(__fadd_rn(w0v, w1v), w2v);
    const int p = batch * NPTS + n;
    oidx[3 * p + 0] = i0; oidx[3 * p + 1] = i1; oidx[3 * p + 2] = i2;
    ow[3 * p + 0] = w0v / sum; ow[3 * p + 1] = w1v / sum; ow[3 * p + 2] = w2v / sum;
    return;
  }

  if (bid == 3168) {
    // ---- BN param folding
    const int t = threadIdx.x;
    if (t < 512) {
      float s = g0[t] / sqrtf(v0[t] + 1e-3f);
      sc0[t] = s;
      sh0[t] = (b0[t] - m0[t]) * s + be0[t];
    }
    if (t < 256) {
      float s = g1[t] / sqrtf(v1[t] + 1e-3f);
      sc1[t] = s;
      sh1[t] = (b1[t] - m1[t]) * s + be1[t];
    }
    return;
  }

  // ---- tiled transpose + f32->bf16 cast (512 threads: 8 rows/iter)
  float (*tile)[65] = reinterpret_cast<float(*)[65]>(ldsbuf);  // 16640B
  const float* in; unsigned short* out;
  int cols, tpr, ldo, tl;
  if (bid < 2560) {
    const int i1b = bid - 512; const int b = i1b >> 9; tl = i1b & 511;
    in = points1 + (size_t)b * DF * NPTS;
    out = Abuf + (size_t)b * NPTS * CIN;
    cols = NPTS; tpr = 128; ldo = CIN;
  } else if (bid < 3072) {
    const int i2b = bid - 2560; const int b = i2b >> 7; tl = i2b & 127;
    in = points2 + (size_t)b * DF * SPTS;
    out = P2T + (size_t)b * SPTS * DF;
    cols = SPTS; tpr = 32; ldo = DF;
  } else if (bid < 3136) {
    tl = bid - 3072; in = w0; out = W0T; cols = 512; tpr = 8; ldo = 512;
  } else {
    tl = bid - 3136; in = w1; out = W1T; cols = 256; tpr = 4; ldo = 512;
  }
  const int tr = (tl / tpr) * 64, tc = (tl % tpr) * 64;
  const int lx = threadIdx.x & 63, ly = threadIdx.x >> 6;
#pragma unroll
  for (int i = ly; i < 64; i += 8)
    tile[i][lx] = in[(size_t)(tr + i) * cols + tc + lx];
  __syncthreads();
#pragma unroll
  for (int i = ly; i < 64; i += 8)
    out[(size_t)(tc + i) * ldo + tr + lx] = f2b(tile[lx][i]);
}

// ---------------- interpolation: 2 points per wave (32 lanes x 16B per row).
__global__ __launch_bounds__(256) void interp_kernel(
    const unsigned short* __restrict__ p2t, const int* __restrict__ oidx,
    const float* __restrict__ ow, unsigned short* __restrict__ A) {
  const int l = threadIdx.x & 63;
  const int lo = l & 31;
  const int p = blockIdx.x * 8 + ((threadIdx.x >> 6) << 1) + (l >> 5);
  const int b = p >> 13;
  float a[8] = {};
#pragma unroll
  for (int k = 0; k < 3; ++k) {
    const int id = oidx[3 * p + k];
    const float w = ow[3 * p + k];
    const unsigned short* row = p2t + ((size_t)b * SPTS + id) * DF + lo * 8;
    u32x4 v = *reinterpret_cast<const u32x4*>(row);
#pragma unroll
    for (int j = 0; j < 4; ++j) {
      a[2 * j + 0] = __builtin_fmaf(w, b2f((unsigned short)(v[j] & 0xffff)), a[2 * j + 0]);
      a[2 * j + 1] = __builtin_fmaf(w, b2f((unsigned short)(v[j] >> 16)), a[2 * j + 1]);
    }
  }
  u32x4 o;
#pragma unroll
  for (int j = 0; j < 4; ++j)
    o[j] = (unsigned)f2b(a[2 * j + 0]) | ((unsigned)f2b(a[2 * j + 1]) << 16);
  *reinterpret_cast<u32x4*>(A + (size_t)p * CIN + DF + lo * 8) = o;
}

// ---------------- GEMM1: 256x256 tile, BK=64, 8 waves (2Mx4N), acc[8][4].
// H[M,512] = bf16(relu((A[M,512]*W0T^T)*scale+shift)). 2-phase dbuf,
// global_load_lds w16 pre-swizzled source, 128KB LDS.
__global__ __launch_bounds__(512, 2) void gemm1_kernel(
    const unsigned short* __restrict__ Abuf, const unsigned short* __restrict__ BT,
    const float* __restrict__ scale, const float* __restrict__ shift,
    unsigned short* __restrict__ H) {
  __shared__ u32x4 lsA[2][2048];  // 64KB
  __shared__ u32x4 lsB[2][2048];  // 64KB
  const int wg = (blockIdx.x & 7) * (gridDim.x >> 3) + (blockIdx.x >> 3);
  const int bn = wg & 1, bm = wg >> 1;
  const int t = threadIdx.x;
  const int lane = t & 63, wave = t >> 6;
  const int wm = wave >> 2, wn = wave & 3;  // 2 M-slabs(128) x 4 N-slabs(64)
  f32x4 acc[8][4] = {};
  const size_t arow0 = (size_t)bm * 256;
  const size_t brow0 = (size_t)bn * 256;

  auto stage = [&](int buf, int kb) {
    const int kbase = kb * 64;
#pragma unroll
    for (int i = 0; i < 4; ++i) {
      const int c = t + 512 * i;            // chunk 0..2047
      const int row = c >> 3;
      const int k16 = (c & 7) ^ (row & 7);  // inverse-swizzled source
      gload16(Abuf + (arow0 + row) * 512 + kbase + k16 * 8,
              &lsA[buf][512 * i + wave * 64]);
      gload16(BT + (brow0 + row) * 512 + kbase + k16 * 8,
              &lsB[buf][512 * i + wave * 64]);
    }
  };

  stage(0, 0);
  __syncthreads();
  int cur = 0;
  for (int kb = 0; kb < 8; ++kb) {
    if (kb < 7) stage(cur ^ 1, kb + 1);  // async prefetch overlaps compute
#pragma unroll
    for (int kk = 0; kk < 2; ++kk) {
      bf16x8 af[8], bfv[4];
      const int c16 = kk * 4 + (lane >> 4);
#pragma unroll
      for (int mi = 0; mi < 8; ++mi) {
        int row = wm * 128 + mi * 16 + (lane & 15);
        af[mi] = __builtin_bit_cast(bf16x8, lsA[cur][row * 8 + (c16 ^ (row & 7))]);
      }
#pragma unroll
      for (int ni = 0; ni < 4; ++ni) {
        int row = wn * 64 + ni * 16 + (lane & 15);
        bfv[ni] = __builtin_bit_cast(bf16x8, lsB[cur][row * 8 + (c16 ^ (row & 7))]);
      }
#pragma unroll
      for (int mi = 0; mi < 8; ++mi)
#pragma unroll
        for (int ni = 0; ni < 4; ++ni)
          acc[mi][ni] = __builtin_amdgcn_mfma_f32_16x16x32_bf16(af[mi], bfv[ni], acc[mi][ni], 0, 0, 0);
    }
    __syncthreads();
    cur ^= 1;
  }
  const int colb = bn * 256 + wn * 64;
  const int rowb = bm * 256 + wm * 128;
#pragma unroll
  for (int ni = 0; ni < 4; ++ni) {
    const int col = colb + ni * 16 + (lane & 15);
    const float sc = scale[col], shv = shift[col];
#pragma unroll
    for (int mi = 0; mi < 8; ++mi) {
      const int r0 = rowb + mi * 16 + ((lane >> 4) * 4);
#pragma unroll
      for (int j = 0; j < 4; ++j) {
        float v = fmaxf(__builtin_fmaf(acc[mi][ni][j], sc, shv), 0.0f);
        H[(size_t)(r0 + j) * 512 + col] = f2b(v);
      }
    }
  }
}

// ---------------- GEMM2 (128x128, 4 waves, 2-phase dbuf).
// out f32 [B][256][N]: C-tile routed through LDS then coalesced f32x4 stores.
__global__ __launch_bounds__(256) void gemm2_kernel(
    const unsigned short* __restrict__ Abuf, const unsigned short* __restrict__ BT,
    const float* __restrict__ scale, const float* __restrict__ shift,
    float* __restrict__ outp, int gridN) {
  __shared__ u32x4 sh[4096];  // 64KB: [0..2047]=A dbuf, [2048..4095]=B dbuf
  const int wg = (blockIdx.x & 7) * (gridDim.x >> 3) + (blockIdx.x >> 3);
  const int bn = wg % gridN, bm = wg / gridN;
  const int t = threadIdx.x;
  const int lane = t & 63, wave = t >> 6;
  const int wm = wave >> 1, wn = wave & 1;
  f32x4 acc[4][4] = {};
  const size_t arow0 = (size_t)bm * 128;
  const size_t brow0 = (size_t)bn * 128;

  auto stage = [&](int buf, int kb) {
    const int kbase = kb * 64;
#pragma unroll
    for (int i = 0; i < 4; ++i) {
      const int c = wave * 256 + i * 64 + lane;     // chunk index 0..1023
      const int row = c >> 3;
      const int k16 = (c & 7) ^ (row & 7);          // inverse-swizzled source
      gload16(Abuf + (arow0 + row) * 512 + kbase + k16 * 8,
              &sh[buf * 1024 + wave * 256 + i * 64]);
      gload16(BT + (brow0 + row) * 512 + kbase + k16 * 8,
              &sh[2048 + buf * 1024 + wave * 256 + i * 64]);
    }
  };

  stage(0, 0);
  __syncthreads();
  int cur = 0;
  for (int kb = 0; kb < 8; ++kb) {
    if (kb < 7) stage(cur ^ 1, kb + 1);
#pragma unroll
    for (int kk = 0; kk < 2; ++kk) {
      bf16x8 af[4], bfv[4];
      const int c16 = kk * 4 + (lane >> 4);
#pragma unroll
      for (int mi = 0; mi < 4; ++mi) {
        int row = wm * 64 + mi * 16 + (lane & 15);
        af[mi] = __builtin_bit_cast(bf16x8, sh[cur * 1024 + row * 8 + (c16 ^ (row & 7))]);
      }
#pragma unroll
      for (int ni = 0; ni < 4; ++ni) {
        int row = wn * 64 + ni * 16 + (lane & 15);
        bfv[ni] = __builtin_bit_cast(bf16x8, sh[2048 + cur * 1024 + row * 8 + (c16 ^ (row & 7))]);
      }
#pragma unroll
      for (int mi = 0; mi < 4; ++mi)
#pragma unroll
        for (int ni = 0; ni < 4; ++ni)
          acc[mi][ni] = __builtin_amdgcn_mfma_f32_16x16x32_bf16(af[mi], bfv[ni], acc[mi][ni], 0, 0, 0);
    }
    __syncthreads();
    cur ^= 1;
  }

  // phase 1: dump 128x128 f32 C-tile into LDS, chunk-XOR swizzled
  f32x4* cf = reinterpret_cast<f32x4*>(sh);
#pragma unroll
  for (int ni = 0; ni < 4; ++ni) {
    const int c = wn * 64 + ni * 16 + (lane & 15);
#pragma unroll
    for (int mi = 0; mi < 4; ++mi) {
      const int rj = (wm * 64 + mi * 16 + ((lane >> 4) * 4)) >> 2;
      cf[c * 32 + (rj ^ (c & 7))] = acc[mi][ni];
    }
  }
  __syncthreads();
  // phase 2: coalesced stores — 32 lanes sweep rj for a fixed channel c
  const int b = (bm * 128) >> 13;
  const int n0 = (bm * 128) & 8191;
#pragma unroll
  for (int i = 0; i < 16; ++i) {
    const int ch = t + i * 256;            // 0..4095
    const int c = ch >> 5, rj = ch & 31;
    f32x4 v = cf[c * 32 + (rj ^ (c & 7))];
    const int col = bn * 128 + c;
    const float sc = scale[col], shv = shift[col];
    f32x4 o;
    o.x = fmaxf(__builtin_fmaf(v.x, sc, shv), 0.0f);
    o.y = fmaxf(__builtin_fmaf(v.y, sc, shv), 0.0f);
    o.z = fmaxf(__builtin_fmaf(v.z, sc, shv), 0.0f);
    o.w = fmaxf(__builtin_fmaf(v.w, sc, shv), 0.0f);
    *reinterpret_cast<f32x4*>(&outp[(((size_t)b * 256 + col) << 13) + n0 + rj * 4]) = o;
  }
}

extern "C" void kernel_launch(void* const* d_in, const int* in_sizes, int n_in,
                              void* d_out, int out_size, void* d_ws, size_t ws_size,
                              hipStream_t stream) {
  const float* xyz1 = (const float*)d_in[0];
  const float* xyz2 = (const float*)d_in[1];
  const float* points1 = (const float*)d_in[2];
  const float* points2 = (const float*)d_in[3];
  const float* w0 = (const float*)d_in[4];
  const float* b0 = (const float*)d_in[5];
  const float* g0 = (const float*)d_in[6];
  const float* be0 = (const float*)d_in[7];
  const float* m0 = (const float*)d_in[8];
  const float* v0 = (const float*)d_in[9];
  const float* w1 = (const float*)d_in[10];
  const float* b1 = (const float*)d_in[11];
  const float* g1 = (const float*)d_in[12];
  const float* be1 = (const float*)d_in[13];
  const float* m1 = (const float*)d_in[14];
  const float* v1 = (const float*)d_in[15];

  char* ws = (char*)d_ws;
  size_t off = 0;
  auto alloc = [&](size_t bytes) {
    void* p = ws + off;
    off += (bytes + 255) & ~(size_t)255;
    return p;
  };
  unsigned short* Abuf = (unsigned short*)alloc((size_t)MTOT * CIN * 2);   // 32 MB
  unsigned short* Hbuf = (unsigned short*)alloc((size_t)MTOT * 512 * 2);   // 32 MB
  unsigned short* W0T  = (unsigned short*)alloc((size_t)512 * 512 * 2);
  unsigned short* W1T  = (unsigned short*)alloc((size_t)256 * 512 * 2);
  unsigned short* P2T  = (unsigned short*)alloc((size_t)NB * SPTS * DF * 2);
  int*   oidx = (int*)alloc((size_t)MTOT * 3 * 4);
  float* ow   = (float*)alloc((size_t)MTOT * 3 * 4);
  float* sc0 = (float*)alloc(512 * 4);
  float* sh0 = (float*)alloc(512 * 4);
  float* sc1 = (float*)alloc(256 * 4);
  float* sh1 = (float*)alloc(256 * 4);
  (void)ws_size; (void)in_sizes; (void)n_in; (void)out_size;

  preknn_kernel<<<3169, 512, 0, stream>>>(xyz1, xyz2, points1, points2, w0, w1,
                                          Abuf, P2T, W0T, W1T, oidx, ow,
                                          b0, g0, be0, m0, v0,
                                          b1, g1, be1, m1, v1,
                                          sc0, sh0, sc1, sh1);
  interp_kernel<<<MTOT / 8, 256, 0, stream>>>(P2T, oidx, ow, Abuf);
  gemm1_kernel<<<dim3(256), 512, 0, stream>>>(Abuf, W0T, sc0, sh0, Hbuf);
  gemm2_kernel<<<dim3(256 * 2), 256, 0, stream>>>(Hbuf, W1T, sc1, sh1, (float*)d_out, 2);
}